// Round 2
// 685.431 us; speedup vs baseline: 1.4127x; 1.4127x over previous
//
#include <hip/hip_runtime.h>
#include <math.h>

#define BN 4
#define HN 96
#define WN 312
#define CN 384
#define D1 49
#define HW (HN*WN)          // 29952
#define CVSZ (BN*D1*HW)     // 5,870,592 floats

// ---------------- cost volume kernel ----------------
// cost[d,h,x] = dot(featL[h,x,:], featR[h,x-d,:]) for x>=d else -inf
//
// Channel-major LDS + outer-product register tiling (v2):
//   block = 1 wave (64 threads), x-tile TXC=64, all 49 d in-block.
//   thread (xg = t&15, dg = t>>4) owns x = x0+4*xg+{0..3}, d = 13*dg+{0..12}.
//   Per channel: read Lv[4] + Rv[16] from LDS (20 b32, <=2-way banks = free)
//   and do 52 FMAs -> VALU-bound instead of LDS-bound.
//   Ls[c][x]   stride 65  (65 mod 32 = 1 -> write banks (4cq+k+row)%32, 2-way)
//   Rs[c][rho] stride 117 (4 pad rows at front so hot loop needs no clamp;
//                          reads hit each bank with exactly 2 lanes)
#define TXC 64
#define KCC 16
#define LSTRIDE 65
#define RSTRIDE 117

__global__ __launch_bounds__(64)
void k_cost(const float* __restrict__ Lf, const float* __restrict__ Rf, float* __restrict__ cv)
{
    __shared__ float Ls[KCC * LSTRIDE];   // 4160 B
    __shared__ float Rs[KCC * RSTRIDE];   // 7488 B
    const int t = threadIdx.x;
    const int xg = t & 15;
    const int dg = t >> 4;
    const int x0 = blockIdx.x * TXC;
    const int h = blockIdx.y;
    const int b = blockIdx.z;
    const float* Lrow = Lf + (size_t)(b * HN + h) * WN * CN;
    const float* Rrow = Rf + (size_t)(b * HN + h) * WN * CN;

    // R local row for (x,d): rho' = 4 + (x - d) - (x0 - 48) = rbase0 + (i + 12 - j)
    const int rbase0 = 40 + 4 * xg - 13 * dg;   // in [1, 100]

    float acc[13][4];
#pragma unroll
    for (int j = 0; j < 13; j++)
#pragma unroll
        for (int i = 0; i < 4; i++) acc[j][i] = 0.f;

    for (int c0 = 0; c0 < CN; c0 += KCC) {
        __syncthreads();
        // stage L: 64 rows x 4 quads (16 channels) = 256 quads -> 4 per thread
#pragma unroll
        for (int ii = 0; ii < 4; ii++) {
            int idx = t + ii * 64;
            int row = idx >> 2, cq = idx & 3;
            int gx = x0 + row;
            float4 v = make_float4(0.f, 0.f, 0.f, 0.f);
            if (gx < WN) v = *(const float4*)(Lrow + (size_t)gx * CN + c0 + cq * 4);
            Ls[(4 * cq + 0) * LSTRIDE + row] = v.x;
            Ls[(4 * cq + 1) * LSTRIDE + row] = v.y;
            Ls[(4 * cq + 2) * LSTRIDE + row] = v.z;
            Ls[(4 * cq + 3) * LSTRIDE + row] = v.w;
        }
        // stage R: 112 rows x 4 quads = 448 quads -> 7 per thread
#pragma unroll
        for (int ii = 0; ii < 7; ii++) {
            int idx = t + ii * 64;
            int row = idx >> 2, cq = idx & 3;
            int gx = x0 - 48 + row;
            float4 v = make_float4(0.f, 0.f, 0.f, 0.f);
            if (gx >= 0 && gx < WN) v = *(const float4*)(Rrow + (size_t)gx * CN + c0 + cq * 4);
            Rs[(4 * cq + 0) * RSTRIDE + row + 4] = v.x;
            Rs[(4 * cq + 1) * RSTRIDE + row + 4] = v.y;
            Rs[(4 * cq + 2) * RSTRIDE + row + 4] = v.z;
            Rs[(4 * cq + 3) * RSTRIDE + row + 4] = v.w;
        }
        __syncthreads();

#pragma unroll
        for (int c = 0; c < KCC; c++) {
            const float* lp = &Ls[c * LSTRIDE + 4 * xg];
            const float* rp = &Rs[c * RSTRIDE + rbase0];
            float Lv0 = lp[0], Lv1 = lp[1], Lv2 = lp[2], Lv3 = lp[3];
            float Rv[16];
#pragma unroll
            for (int r = 0; r < 16; r++) Rv[r] = rp[r];
#pragma unroll
            for (int j = 0; j < 13; j++) {
                acc[j][0] = fmaf(Lv0, Rv[12 - j + 0], acc[j][0]);
                acc[j][1] = fmaf(Lv1, Rv[12 - j + 1], acc[j][1]);
                acc[j][2] = fmaf(Lv2, Rv[12 - j + 2], acc[j][2]);
                acc[j][3] = fmaf(Lv3, Rv[12 - j + 3], acc[j][3]);
            }
        }
    }

    const float NINF = -__builtin_inff();
#pragma unroll
    for (int j = 0; j < 13; j++) {
        int d = 13 * dg + j;
        if (d < D1) {
            size_t base = ((size_t)(b * D1 + d) * HN + h) * WN;
            int x = x0 + 4 * xg;
            float v0 = (x + 0 >= d) ? acc[j][0] : NINF;
            float v1 = (x + 1 >= d) ? acc[j][1] : NINF;
            float v2 = (x + 2 >= d) ? acc[j][2] : NINF;
            float v3 = (x + 3 >= d) ? acc[j][3] : NINF;
            if (x + 3 < WN) {
                *(float4*)(cv + base + x) = make_float4(v0, v1, v2, v3);
            } else {
                if (x + 0 < WN) cv[base + x + 0] = v0;
                if (x + 1 < WN) cv[base + x + 1] = v1;
                if (x + 2 < WN) cv[base + x + 2] = v2;
                if (x + 3 < WN) cv[base + x + 3] = v3;
            }
        }
    }
}

// ---------------- entropy kernel ----------------
__global__ void k_entropy(const float* __restrict__ cv, float* __restrict__ ent)
{
    int i = blockIdx.x * 256 + threadIdx.x;
    if (i >= BN * HW) return;
    int b = i / HW;
    int r = i - b * HW;
    const float* p = cv + (size_t)b * D1 * HW + r;
    float v[D1];
#pragma unroll
    for (int d = 0; d < D1; d++) v[d] = p[(size_t)d * HW];

    float m = v[0];
#pragma unroll
    for (int d = 1; d < D1; d++) m = fmaxf(m, v[d]);

    float S = 0.f;
    int cnt = 0;
#pragma unroll
    for (int d = 0; d < D1; d++) {
        if (isfinite(v[d])) cnt++;
        S += expf((v[d] - m) * 10.0f);
    }
    float lS = logf(S);
    float e_acc = 0.f;
#pragma unroll
    for (int d = 0; d < D1; d++) {
        float l = (v[d] - m) * 10.0f;
        float pe = expf(l) / S;
        if (pe > 1e-8f) e_acc -= pe * (l - lS);
        else            e_acc += 1.8420681e-7f;  // -1e-8*ln(1e-8)
    }
    float out = 0.f;
    if (cnt > 1) out = e_acc / (logf((float)cnt) + 1e-8f);
    out = fminf(fmaxf(out, 0.f), 1.f);
    ent[i] = out;
}

// ---------------- run extents + refine mask ----------------
// ROI (precomputed from Python float semantics): rows [64,95], cols [62,218]
__global__ void k_extents(const float* __restrict__ ent, int* __restrict__ Aa,
                          int* __restrict__ Bb, unsigned char* __restrict__ rm)
{
    int row = blockIdx.x * 64 + threadIdx.x;
    if (row >= BN * HN) return;
    int h = row % HN;
    const float* er = ent + (size_t)row * WN;
    int* Ar = Aa + (size_t)row * WN;
    int* Br = Bb + (size_t)row * WN;
    unsigned char* mr = rm + (size_t)row * WN;
    const bool roi_row = (h >= 64 && h <= 95);

    int prev = -1;
    for (int x = 0; x < WN; x++) {
        bool val = er[x] <= 0.6f;
        if (val) prev = x;
        int L0 = x - prev - 1; if (L0 < 0) L0 = 0;
        int a = x - L0; if (a < 0) a = 0;
        int lo = x - 12; if (lo < 0) lo = 0;
        if (a < lo) a = lo;
        Ar[x] = a;
    }
    int nxt = WN;
    for (int x = WN - 1; x >= 0; x--) {
        bool val = er[x] <= 0.6f;
        if (val) nxt = x;
        int R0 = nxt - x - 1; if (R0 < 0) R0 = 0;
        int bb = x + R0; if (bb > WN - 1) bb = WN - 1;
        int hi = x + 12; if (hi > WN - 1) hi = WN - 1;
        if (bb > hi) bb = hi;
        Br[x] = bb;
        mr[x] = (!val && roi_row && x >= 62 && x <= 218) ? 1 : 0;
    }
}

// ---------------- windowed refine ----------------
__global__ void k_refine(const float* __restrict__ cvin, float* __restrict__ cvout,
                         const int* __restrict__ Aa, const int* __restrict__ Bb,
                         const unsigned char* __restrict__ rm)
{
    int r = blockIdx.x * 256 + threadIdx.x;   // grid.x = HW/256 = 117 exact
    int d = blockIdx.y, b = blockIdx.z;
    int h = r / WN, x = r - h * WN;
    size_t rowbase = ((size_t)(b * D1 + d) * HN + h) * WN;
    size_t idx = rowbase + x;
    int mi = b * HW + r;
    float vin = cvin[idx];
    float out;
    if (!rm[mi]) {
        out = vin;
    } else {
        int a = Aa[mi], bb = Bb[mi];
        const float* rowp = cvin + rowbase;
        float num = 0.f; int den = 0;
        for (int xx = a; xx <= bb; xx++) {
            float v = rowp[xx];
            if (isfinite(v)) { num += v; den++; }
        }
        out = (den > 0) ? num / (float)den : -__builtin_inff();
    }
    cvout[idx] = out;
}

// ---------------- loss kernel ----------------
__global__ void k_loss(const float* __restrict__ cv2, const unsigned char* __restrict__ rm,
                       const float* __restrict__ student, float* __restrict__ accum)
{
    int r = blockIdx.x * 256 + threadIdx.x;  // grid.x = 117
    int b = blockIdx.y;
    int i = b * HW + r;
    float sl1 = 0.f, msk = 0.f;
    if (rm[i]) {
        const float* p = cv2 + (size_t)b * D1 * HW + r;
        float best = p[0]; int bi = 0;
#pragma unroll
        for (int d = 1; d < D1; d++) {
            float v = p[(size_t)d * HW];
            if (v > best) { best = v; bi = d; }   // first-max tie-break (ascending, strict >)
        }
        float diff = student[i] * 0.25f - (float)bi;
        float ad = fabsf(diff);
        sl1 = (ad < 1.f) ? 0.5f * ad * ad : ad - 0.5f;
        msk = 1.f;
    }
#pragma unroll
    for (int off = 32; off; off >>= 1) {
        sl1 += __shfl_down(sl1, off);
        msk += __shfl_down(msk, off);
    }
    __shared__ float s1[4], s2[4];
    int w = threadIdx.x >> 6, lane = threadIdx.x & 63;
    if (lane == 0) { s1[w] = sl1; s2[w] = msk; }
    __syncthreads();
    if (threadIdx.x == 0) {
        float a = s1[0] + s1[1] + s1[2] + s1[3];
        float c = s2[0] + s2[1] + s2[2] + s2[3];
        atomicAdd(&accum[b * 2], a);
        atomicAdd(&accum[b * 2 + 1], c);
    }
}

__global__ void k_finalize(const float* __restrict__ accum, float* __restrict__ out)
{
    if (threadIdx.x == 0 && blockIdx.x == 0) {
        float s = 0.f;
        for (int b = 0; b < BN; b++) {
            float c = accum[2 * b + 1];
            if (c < 1.f) c = 1.f;
            s += accum[2 * b] / c;
        }
        out[0] = s * 0.25f;
    }
}

extern "C" void kernel_launch(void* const* d_in, const int* in_sizes, int n_in,
                              void* d_out, int out_size, void* d_ws, size_t ws_size,
                              hipStream_t stream)
{
    const float* fL = (const float*)d_in[0];
    const float* fR = (const float*)d_in[1];
    const float* st = (const float*)d_in[2];
    float* out = (float*)d_out;

    float* cv0 = (float*)d_ws;
    float* cv1 = cv0 + CVSZ;
    float* ent = cv1 + CVSZ;
    int* Aa = (int*)(ent + BN * HW);
    int* Bb = Aa + BN * HW;
    unsigned char* rm = (unsigned char*)(Bb + BN * HW);
    float* accum = (float*)(rm + BN * HW);   // BN*HW = 119808, 16B-aligned

    // E0
    k_cost<<<dim3(5, 96, 4), 64, 0, stream>>>(fL, fR, cv0);
    // ent0
    k_entropy<<<dim3((BN * HW + 255) / 256), 256, 0, stream>>>(cv0, ent);
    // extents1 + rm1
    k_extents<<<dim3(6), 64, 0, stream>>>(ent, Aa, Bb, rm);
    // E1
    k_refine<<<dim3(117, D1, BN), 256, 0, stream>>>(cv0, cv1, Aa, Bb, rm);
    // ent1
    k_entropy<<<dim3((BN * HW + 255) / 256), 256, 0, stream>>>(cv1, ent);
    // extents2 + rm2
    k_extents<<<dim3(6), 64, 0, stream>>>(ent, Aa, Bb, rm);
    // E2
    k_refine<<<dim3(117, D1, BN), 256, 0, stream>>>(cv1, cv0, Aa, Bb, rm);
    // loss
    hipMemsetAsync(accum, 0, 8 * sizeof(float), stream);
    k_loss<<<dim3(117, BN), 256, 0, stream>>>(cv0, rm, st, accum);
    k_finalize<<<1, 64, 0, stream>>>(accum, out);
}